// Round 12
// baseline (801.932 us; speedup 1.0000x reference)
//
#include <hip/hip_runtime.h>
#include <cstdint>

#define N_NODES 50000
#define N_EDGES 800000
#define EP (N_EDGES + N_NODES)   // edges + self-loops
#define IN_DIM 32
#define HID 64
#define HEADS 4
#define HC 256                   // HID*HEADS
#define OUT_DIM 128
#define NEG_SLOPE 0.2f
#define LN_EPS 1e-5f
#define SCAN_B 1024
#define NB ((N_NODES + SCAN_B - 1) / SCAN_B)   // 49
#define AGG_BLOCKS (N_NODES / 8)               // 6250
#define LIN_BLOCKS ((N_NODES + 63) / 64)       // 782
#define OUT_BLOCKS ((N_NODES + 127) / 128)     // 391

typedef __attribute__((ext_vector_type(8))) short bf16x8;
typedef __attribute__((ext_vector_type(16))) float f32x16;

__device__ __forceinline__ unsigned bf16rne(float f) {
    unsigned u = __float_as_uint(f);
    return (u + 0x7fffu + ((u >> 16) & 1u)) >> 16;
}
__device__ __forceinline__ unsigned pack_bf2(float a, float b) {
    return bf16rne(a) | (bf16rne(b) << 16);
}
__device__ __forceinline__ float bf_lo(unsigned w) { return __uint_as_float(w << 16); }
__device__ __forceinline__ float bf_hi_raw(unsigned w) { return __uint_as_float(w); }

// ===== fused prep: in_proj | weight pack | att-ext columns | edge histogram =====
#define PREP_INPROJ ((N_NODES * HID) / 256)                    // 12500
#define PREP_WPACK ((HID * HC + HC * HC + HC * OUT_DIM) / 256) // 448
#define PREP_EXT 40
#define PREP_HIST ((EP + 255) / 256)                           // 3321
__global__ void k_prep(const float* __restrict__ x, const float* __restrict__ W_in,
                       const float* __restrict__ b_in, unsigned short* __restrict__ h_in,
                       const float* __restrict__ w0, const float* __restrict__ w1,
                       const float* __restrict__ w2, unsigned short* __restrict__ p0,
                       unsigned short* __restrict__ p1, unsigned short* __restrict__ p2,
                       const float* __restrict__ as0, const float* __restrict__ ad0,
                       unsigned short* __restrict__ ext0,
                       const float* __restrict__ as1, const float* __restrict__ ad1,
                       unsigned short* __restrict__ ext1,
                       const int* __restrict__ ei, int* __restrict__ counts,
                       int* __restrict__ rank) {
    if (blockIdx.x < PREP_INPROJ) {
        int g = blockIdx.x * 256 + threadIdx.x;
        int n = g >> 6, j = g & 63;
        const float* xr = x + n * IN_DIM;
        float acc = b_in[j];
#pragma unroll
        for (int k = 0; k < IN_DIM; ++k) acc += xr[k] * W_in[k * HID + j];
        acc = acc > 0.f ? acc : (__expf(acc) - 1.f);
        h_in[g] = (unsigned short)bf16rne(acc);
    } else if (blockIdx.x < PREP_INPROJ + PREP_WPACK) {
        int g = (blockIdx.x - PREP_INPROJ) * 256 + threadIdx.x;
        if (g < HID * HC) {
            int k = g >> 8, n = g & 255;
            p0[(((k >> 3) * HC) + n) * 8 + (k & 7)] = (unsigned short)bf16rne(w0[g]);
        } else if (g < HID * HC + HC * HC) {
            int t = g - HID * HC;
            int k = t >> 8, n = t & 255;
            p1[(((k >> 3) * HC) + n) * 8 + (k & 7)] = (unsigned short)bf16rne(w1[t]);
        } else {
            int t = g - HID * HC - HC * HC;
            int k = t >> 7, n = t & 127;
            p2[(((k >> 3) * OUT_DIM) + n) * 8 + (k & 7)] = (unsigned short)bf16rne(w2[t]);
        }
    } else if (blockIdx.x < PREP_INPROJ + PREP_WPACK + PREP_EXT) {
        int t = (blockIdx.x - PREP_INPROJ - PREP_WPACK) * 256 + threadIdx.x;
        const float* w; const float* as; const float* ad; unsigned short* ext; int e;
        if (t < 2048) { w = w0; as = as0; ad = ad0; ext = ext0; e = t; }
        else if (t < 2048 + 8192) { w = w1; as = as1; ad = ad1; ext = ext1; e = t - 2048; }
        else return;
        int kb = e >> 8, rem = e & 255, col = rem >> 3, kk = rem & 7;
        int k = kb * 8 + kk;
        float acc = 0.f;
        if (col < 8) {
            int h = col & 3;
            const float* att = (col < 4) ? as : ad;
#pragma unroll 4
            for (int c = 0; c < HID; ++c) acc += w[k * HC + h * HID + c] * att[h * HID + c];
        }
        ext[e] = (unsigned short)bf16rne(acc);
    } else {
        int e = (blockIdx.x - PREP_INPROJ - PREP_WPACK - PREP_EXT) * 256 + threadIdx.x;
        if (e >= EP) return;
        int d = (e < N_EDGES) ? ei[N_EDGES + e] : (e - N_EDGES);
        rank[e] = atomicAdd(&counts[d], 1);
    }
}

// ===== single-launch scan: 49 co-resident blocks + device-scope release spin =====
__global__ void k_scan(const int* __restrict__ counts, int* __restrict__ bsum,
                       int* __restrict__ done, int* __restrict__ row_ptr) {
    __shared__ int buf[SCAN_B];
    __shared__ int sbase;
    int i = blockIdx.x * SCAN_B + threadIdx.x;
    int v = (i < N_NODES) ? counts[i] : 0;
    buf[threadIdx.x] = v;
    __syncthreads();
    for (int off = 1; off < SCAN_B; off <<= 1) {
        int t = (threadIdx.x >= off) ? buf[threadIdx.x - off] : 0;
        __syncthreads();
        buf[threadIdx.x] += t;
        __syncthreads();
    }
    int excl = buf[threadIdx.x] - v;
    if (threadIdx.x == SCAN_B - 1) {
        bsum[blockIdx.x] = buf[SCAN_B - 1];
        __threadfence();
        atomicAdd(done, 1);
    }
    if (threadIdx.x == 0) {
        while (__hip_atomic_load(done, __ATOMIC_RELAXED, __HIP_MEMORY_SCOPE_AGENT) < NB) {
            __builtin_amdgcn_s_sleep(8);
        }
    }
    __syncthreads();
    if (threadIdx.x < 64) {
        int t = threadIdx.x;
        int val = (t < blockIdx.x)
                ? __hip_atomic_load(&bsum[t], __ATOMIC_RELAXED, __HIP_MEMORY_SCOPE_AGENT) : 0;
#pragma unroll
        for (int mk = 1; mk < 64; mk <<= 1) val += __shfl_xor(val, mk, 64);
        if (t == 0) sbase = val;
    }
    __syncthreads();
    if (i < N_NODES) row_ptr[i] = excl + sbase;
    if (i == 0) row_ptr[N_NODES] = EP;
}

// ======= MFMA GEMM body (bf16): hh[M,256] = A[M,K] @ B[K,256]; odd waves also =====
// ======= compute the 8 attention-dot columns -> a_src/a_dst directly ==============
template <int K>
__device__ __forceinline__ void gemm_lin_body(
        int mblk, const unsigned short* __restrict__ A, const unsigned short* __restrict__ Bp,
        const unsigned short* __restrict__ Ext, unsigned short* __restrict__ hh,
        float* __restrict__ a_src, float* __restrict__ a_dst) {
    const int lane = threadIdx.x & 63;
    const int quad = lane >> 5, c = lane & 31;
    const int wave = threadIdx.x >> 6;
    const int m0 = mblk * 64 + (wave >> 1) * 32;
    const int cb = (wave & 1) * 128;
    f32x16 acc[4];
#pragma unroll
    for (int nt = 0; nt < 4; ++nt)
#pragma unroll
        for (int i = 0; i < 16; ++i) acc[nt][i] = 0.f;
    f32x16 acce;
#pragma unroll
    for (int i = 0; i < 16; ++i) acce[i] = 0.f;
    int mrow = m0 + c; if (mrow >= N_NODES) mrow = N_NODES - 1;
    const size_t abase = (size_t)mrow * K + quad * 8;
    for (int k0 = 0; k0 < K; k0 += 16) {
        bf16x8 af = *(const bf16x8*)(A + abase + k0);
        const unsigned short* bk = Bp + ((size_t)(k0 >> 3) + quad) * (HC * 8);
#pragma unroll
        for (int nt = 0; nt < 4; ++nt) {
            bf16x8 bf = *(const bf16x8*)(bk + (cb + nt * 32 + c) * 8);
            acc[nt] = __builtin_amdgcn_mfma_f32_32x32x16_bf16(af, bf, acc[nt], 0, 0, 0);
        }
        if (wave & 1) {
            bf16x8 bfe = *(const bf16x8*)(Ext + ((k0 >> 3) + quad) * 256 + c * 8);
            acce = __builtin_amdgcn_mfma_f32_32x32x16_bf16(af, bfe, acce, 0, 0, 0);
        }
    }
#pragma unroll
    for (int reg = 0; reg < 16; ++reg) {
        int row = (reg & 3) + 8 * (reg >> 2) + 4 * quad;
        int m = m0 + row;
        if (m < N_NODES) {
            size_t base = (size_t)m * HC + cb + c;
#pragma unroll
            for (int nt = 0; nt < 4; ++nt)
                hh[base + nt * 32] = (unsigned short)bf16rne(acc[nt][reg]);
            if ((wave & 1) && c < 8) {
                float v = acce[reg];
                if (c < 4) a_src[m * HEADS + c] = v;
                else       a_dst[m * HEADS + (c - 4)] = v;
            }
        }
    }
}

// ======= layer-0 GEMM fused with CSR scatter =======
__global__ __launch_bounds__(256) void k_gemm0_scatter(
        const unsigned short* __restrict__ A, const unsigned short* __restrict__ Bp,
        const unsigned short* __restrict__ Ext, unsigned short* __restrict__ hh,
        float* __restrict__ a_src, float* __restrict__ a_dst,
        const int* __restrict__ ei, const int* __restrict__ row_ptr,
        const int* __restrict__ rank, int* __restrict__ esrc) {
    if (blockIdx.x < LIN_BLOCKS) {
        gemm_lin_body<HID>(blockIdx.x, A, Bp, Ext, hh, a_src, a_dst);
        return;
    }
    int e = (blockIdx.x - LIN_BLOCKS) * 256 + threadIdx.x;
    if (e < EP) {
        int s, d;
        if (e < N_EDGES) { s = ei[e]; d = ei[N_EDGES + e]; } else { s = d = e - N_EDGES; }
        esrc[row_ptr[d] + rank[e]] = s;
    } else if (e - EP < 64) {
        esrc[e] = 0;                     // pad tail so agg chunk loads need no clamp
    }
}

// ===== GAT aggregate body: HALF-wave per dst node, lane owns 8 cols (uint4) =====
__device__ __forceinline__ void agg_body(
        int blk, const int* __restrict__ row_ptr, const int* __restrict__ esrc,
        const unsigned short* __restrict__ hh, const float* __restrict__ a_src,
        const float* __restrict__ a_dst, const float* __restrict__ bias,
        unsigned short* __restrict__ out) {
    const int wave = threadIdx.x >> 6;
    const int lane = threadIdx.x & 63;
    const int half = lane >> 5;
    const int l = lane & 31;
    const int d = blk * 8 + wave * 2 + half;
    const int h = l >> 3;
    const unsigned c0 = (unsigned)(l * 8);
    const int bsrc = half << 5;
    const float ad = a_dst[((unsigned)d << 2) + h];
    const int beg = row_ptr[d], end = row_ptr[d + 1];
    float acc[8];
#pragma unroll
    for (int t = 0; t < 8; ++t) acc[t] = 0.f;
    float psum = 0.f;
    int myv = esrc[beg + l];
    for (int base = beg; base < end; base += 32) {
        int rem = end - base;
        int cnt = rem > 32 ? 32 : rem;
        int nxt = 0;
        if (rem > 32) nxt = esrc[base + 32 + l];
        int i = 0;
        for (; i + 4 <= cnt; i += 4) {
            int s0 = __shfl(myv, bsrc + i, 64);
            int s1 = __shfl(myv, bsrc + i + 1, 64);
            int s2 = __shfl(myv, bsrc + i + 2, 64);
            int s3 = __shfl(myv, bsrc + i + 3, 64);
            float as0 = a_src[((unsigned)s0 << 2) + h];
            float as1 = a_src[((unsigned)s1 << 2) + h];
            float as2 = a_src[((unsigned)s2 << 2) + h];
            float as3 = a_src[((unsigned)s3 << 2) + h];
            uint4 g0 = *(const uint4*)(hh + (((size_t)(unsigned)s0 << 8) + c0));
            uint4 g1 = *(const uint4*)(hh + (((size_t)(unsigned)s1 << 8) + c0));
            uint4 g2 = *(const uint4*)(hh + (((size_t)(unsigned)s2 << 8) + c0));
            uint4 g3 = *(const uint4*)(hh + (((size_t)(unsigned)s3 << 8) + c0));
            float e0 = as0 + ad, e1 = as1 + ad, e2 = as2 + ad, e3 = as3 + ad;
            e0 = fmaxf(e0, NEG_SLOPE * e0); e1 = fmaxf(e1, NEG_SLOPE * e1);
            e2 = fmaxf(e2, NEG_SLOPE * e2); e3 = fmaxf(e3, NEG_SLOPE * e3);
            float p0 = __expf(e0), p1 = __expf(e1), p2 = __expf(e2), p3 = __expf(e3);
            psum += (p0 + p1) + (p2 + p3);
            acc[0] += p0 * bf_lo(g0.x) + p1 * bf_lo(g1.x) + p2 * bf_lo(g2.x) + p3 * bf_lo(g3.x);
            acc[1] += p0 * bf_hi_raw(g0.x) + p1 * bf_hi_raw(g1.x) + p2 * bf_hi_raw(g2.x) + p3 * bf_hi_raw(g3.x);
            acc[2] += p0 * bf_lo(g0.y) + p1 * bf_lo(g1.y) + p2 * bf_lo(g2.y) + p3 * bf_lo(g3.y);
            acc[3] += p0 * bf_hi_raw(g0.y) + p1 * bf_hi_raw(g1.y) + p2 * bf_hi_raw(g2.y) + p3 * bf_hi_raw(g3.y);
            acc[4] += p0 * bf_lo(g0.z) + p1 * bf_lo(g1.z) + p2 * bf_lo(g2.z) + p3 * bf_lo(g3.z);
            acc[5] += p0 * bf_hi_raw(g0.z) + p1 * bf_hi_raw(g1.z) + p2 * bf_hi_raw(g2.z) + p3 * bf_hi_raw(g3.z);
            acc[6] += p0 * bf_lo(g0.w) + p1 * bf_lo(g1.w) + p2 * bf_lo(g2.w) + p3 * bf_lo(g3.w);
            acc[7] += p0 * bf_hi_raw(g0.w) + p1 * bf_hi_raw(g1.w) + p2 * bf_hi_raw(g2.w) + p3 * bf_hi_raw(g3.w);
        }
        for (; i < cnt; ++i) {
            int s0 = __shfl(myv, bsrc + i, 64);
            float as0 = a_src[((unsigned)s0 << 2) + h];
            uint4 g0 = *(const uint4*)(hh + (((size_t)(unsigned)s0 << 8) + c0));
            float e0 = as0 + ad;
            e0 = fmaxf(e0, NEG_SLOPE * e0);
            float p0 = __expf(e0);
            psum += p0;
            acc[0] += p0 * bf_lo(g0.x); acc[1] += p0 * bf_hi_raw(g0.x);
            acc[2] += p0 * bf_lo(g0.y); acc[3] += p0 * bf_hi_raw(g0.y);
            acc[4] += p0 * bf_lo(g0.z); acc[5] += p0 * bf_hi_raw(g0.z);
            acc[6] += p0 * bf_lo(g0.w); acc[7] += p0 * bf_hi_raw(g0.w);
        }
        myv = nxt;
    }
    const float inv = 1.f / (psum + 1e-16f);
    const float4 bb0 = *(const float4*)(bias + c0);
    const float4 bb1 = *(const float4*)(bias + c0 + 4);
    float v[8];
    v[0] = acc[0] * inv + bb0.x; v[1] = acc[1] * inv + bb0.y;
    v[2] = acc[2] * inv + bb0.z; v[3] = acc[3] * inv + bb0.w;
    v[4] = acc[4] * inv + bb1.x; v[5] = acc[5] * inv + bb1.y;
    v[6] = acc[6] * inv + bb1.z; v[7] = acc[7] * inv + bb1.w;
#pragma unroll
    for (int t = 0; t < 8; ++t) v[t] = v[t] > 0.f ? v[t] : (__expf(v[t]) - 1.f);
    uint4 pk;
    pk.x = pack_bf2(v[0], v[1]); pk.y = pack_bf2(v[2], v[3]);
    pk.z = pack_bf2(v[4], v[5]); pk.w = pack_bf2(v[6], v[7]);
    *(uint4*)(out + (((size_t)d << 8) + c0)) = pk;
}

// ======= fused: agg layer-0 (producers) + lin1 GEMM (per-64-row consumers) =======
__global__ __launch_bounds__(256) void k_agg_gemm1(
        const int* __restrict__ row_ptr, const int* __restrict__ esrc,
        const unsigned short* __restrict__ hh_a, const float* __restrict__ a_srcA,
        const float* __restrict__ a_dstA, const float* __restrict__ bias0,
        unsigned short* __restrict__ feat,
        const unsigned short* __restrict__ p1, const unsigned short* __restrict__ ext1,
        unsigned short* __restrict__ hh_b, float* __restrict__ a_srcB,
        float* __restrict__ a_dstB, int* __restrict__ cnt1) {
    if (blockIdx.x < AGG_BLOCKS) {
        agg_body(blockIdx.x, row_ptr, esrc, hh_a, a_srcA, a_dstA, bias0, feat);
        __syncthreads();                       // drains vmcnt: stores are in L2
        if (threadIdx.x == 0) {
            __threadfence();                   // release: write back XCD L2
            atomicAdd(&cnt1[blockIdx.x >> 3], 1);
        }
        return;
    }
    const int g = blockIdx.x - AGG_BLOCKS;     // 0..781
    const int target = (8 * g + 8 <= AGG_BLOCKS) ? 8 : (AGG_BLOCKS - 8 * g);
    if (threadIdx.x == 0) {
        while (__hip_atomic_load(&cnt1[g], __ATOMIC_RELAXED, __HIP_MEMORY_SCOPE_AGENT) < target)
            __builtin_amdgcn_s_sleep(2);
        __threadfence();                       // acquire: invalidate stale cache
    }
    __syncthreads();
    gemm_lin_body<HC>(g, feat, p1, ext1, hh_b, a_srcB, a_dstB);
}

// ======= fused: agg layer-1 (producers) + out-proj GEMM + LN (128-row consumers) =======
__global__ __launch_bounds__(256) void k_agg_gemm2(
        const int* __restrict__ row_ptr, const int* __restrict__ esrc,
        const unsigned short* __restrict__ hh_b, const float* __restrict__ a_srcB,
        const float* __restrict__ a_dstB, const float* __restrict__ bias1,
        unsigned short* __restrict__ feat,
        const unsigned short* __restrict__ p2, const float* __restrict__ b,
        const float* __restrict__ gamma, const float* __restrict__ beta,
        float* __restrict__ out, int* __restrict__ cnt2) {
    if (blockIdx.x < AGG_BLOCKS) {
        agg_body(blockIdx.x, row_ptr, esrc, hh_b, a_srcB, a_dstB, bias1, feat);
        __syncthreads();
        if (threadIdx.x == 0) {
            __threadfence();
            atomicAdd(&cnt2[blockIdx.x >> 4], 1);
        }
        return;
    }
    const int g = blockIdx.x - AGG_BLOCKS;     // 0..390
    const int target = (16 * g + 16 <= AGG_BLOCKS) ? 16 : (AGG_BLOCKS - 16 * g);
    if (threadIdx.x == 0) {
        while (__hip_atomic_load(&cnt2[g], __ATOMIC_RELAXED, __HIP_MEMORY_SCOPE_AGENT) < target)
            __builtin_amdgcn_s_sleep(2);
        __threadfence();
    }
    __syncthreads();
    // ---- out-proj + LayerNorm on rows 128g..128g+127 ----
    const int lane = threadIdx.x & 63;
    const int quad = lane >> 5, c = lane & 31;
    const int m0 = g * 128 + (threadIdx.x >> 6) * 32;
    f32x16 acc[4];
#pragma unroll
    for (int nt = 0; nt < 4; ++nt)
#pragma unroll
        for (int i = 0; i < 16; ++i) acc[nt][i] = 0.f;
    int mrow = m0 + c; if (mrow >= N_NODES) mrow = N_NODES - 1;
    const size_t abase = (size_t)mrow * HC + quad * 8;
    for (int k0 = 0; k0 < HC; k0 += 16) {
        bf16x8 af = *(const bf16x8*)(feat + abase + k0);
        const unsigned short* bk = p2 + ((size_t)(k0 >> 3) + quad) * (OUT_DIM * 8);
#pragma unroll
        for (int nt = 0; nt < 4; ++nt) {
            bf16x8 bf = *(const bf16x8*)(bk + (nt * 32 + c) * 8);
            acc[nt] = __builtin_amdgcn_mfma_f32_32x32x16_bf16(af, bf, acc[nt], 0, 0, 0);
        }
    }
    float bb[4], gg[4], be[4];
#pragma unroll
    for (int nt = 0; nt < 4; ++nt) {
        int col = nt * 32 + c;
        bb[nt] = b[col]; gg[nt] = gamma[col]; be[nt] = beta[col];
    }
#pragma unroll
    for (int reg = 0; reg < 16; ++reg) {
        int row = (reg & 3) + 8 * (reg >> 2) + 4 * quad;
        int m = m0 + row;
        float v[4];
        float s = 0.f, s2 = 0.f;
#pragma unroll
        for (int nt = 0; nt < 4; ++nt) {
            v[nt] = acc[nt][reg] + bb[nt];
            s += v[nt]; s2 += v[nt] * v[nt];
        }
#pragma unroll
        for (int mk = 1; mk < 32; mk <<= 1) {
            s += __shfl_xor(s, mk, 64);
            s2 += __shfl_xor(s2, mk, 64);
        }
        float mu = s * (1.f / OUT_DIM);
        float var = s2 * (1.f / OUT_DIM) - mu * mu;
        float inv = rsqrtf(var + LN_EPS);
        if (m < N_NODES) {
            size_t base = (size_t)m * OUT_DIM + c;
#pragma unroll
            for (int nt = 0; nt < 4; ++nt)
                out[base + nt * 32] = (v[nt] - mu) * inv * gg[nt] + be[nt];
        }
    }
}

extern "C" void kernel_launch(void* const* d_in, const int* in_sizes, int n_in,
                              void* d_out, int out_size, void* d_ws, size_t ws_size,
                              hipStream_t stream) {
    const float* x        = (const float*)d_in[0];
    const int*   ei       = (const int*)  d_in[1];
    const float* W_in     = (const float*)d_in[2];
    const float* b_in     = (const float*)d_in[3];
    const float* lin0_w   = (const float*)d_in[4];
    const float* att0_src = (const float*)d_in[5];
    const float* att0_dst = (const float*)d_in[6];
    const float* bias0    = (const float*)d_in[7];
    const float* lin1_w   = (const float*)d_in[8];
    const float* att1_src = (const float*)d_in[9];
    const float* att1_dst = (const float*)d_in[10];
    const float* bias1    = (const float*)d_in[11];
    const float* W_out    = (const float*)d_in[12];
    const float* b_out    = (const float*)d_in[13];
    const float* ln_gamma = (const float*)d_in[14];
    const float* ln_beta  = (const float*)d_in[15];
    float* out = (float*)d_out;

    unsigned short* us = (unsigned short*)d_ws;
    unsigned short* h_in_bf = us;                                  // N*HID
    unsigned short* hh_a    = h_in_bf + (size_t)N_NODES * HID;     // N*HC
    unsigned short* hh_b    = hh_a + (size_t)N_NODES * HC;         // N*HC
    unsigned short* feat_bf = hh_b + (size_t)N_NODES * HC;         // N*HC
    unsigned short* p0      = feat_bf + (size_t)N_NODES * HC;      // 64*256
    unsigned short* p1      = p0 + HID * HC;                       // 256*256
    unsigned short* p2      = p1 + HC * HC;                        // 256*128
    unsigned short* ext0    = p2 + HC * OUT_DIM;                   // 2048
    unsigned short* ext1    = ext0 + 2048;                         // 8192
    float* a_srcA = (float*)(ext1 + 8192);
    float* a_dstA = a_srcA + (size_t)N_NODES * HEADS;
    float* a_srcB = a_dstA + (size_t)N_NODES * HEADS;
    float* a_dstB = a_srcB + (size_t)N_NODES * HEADS;
    int* counts  = (int*)(a_dstB + (size_t)N_NODES * HEADS);       // N
    int* done    = counts + N_NODES;                               // 1
    int* cnt1    = done + 1;                                       // LIN_BLOCKS
    int* cnt2    = cnt1 + LIN_BLOCKS;                              // OUT_BLOCKS
    int* bsum    = cnt2 + OUT_BLOCKS;                              // NB
    int* row_ptr = bsum + NB;                                      // N+1
    int* rank    = row_ptr + N_NODES + 1;                          // EP
    int* esrc    = rank + EP;                                      // EP + 64 (padded)

    // 0. zero counts + done + cnt1 + cnt2 (contiguous)
    hipMemsetAsync(counts, 0, (N_NODES + 1 + LIN_BLOCKS + OUT_BLOCKS) * sizeof(int), stream);

    // 1. fused prep: input proj + weight packing + att columns + edge histogram
    k_prep<<<PREP_INPROJ + PREP_WPACK + PREP_EXT + PREP_HIST, 256, 0, stream>>>(
        x, W_in, b_in, h_in_bf, lin0_w, lin1_w, W_out, p0, p1, p2,
        att0_src, att0_dst, ext0, att1_src, att1_dst, ext1, ei, counts, rank);

    // 2. single-launch scan -> row_ptr
    k_scan<<<NB, SCAN_B, 0, stream>>>(counts, bsum, done, row_ptr);

    // 3. layer-0 GEMM fused with CSR scatter
    k_gemm0_scatter<<<LIN_BLOCKS + PREP_HIST, 256, 0, stream>>>(
        h_in_bf, p0, ext0, hh_a, a_srcA, a_dstA, ei, row_ptr, rank, esrc);

    // 4. fused agg0 + lin1 GEMM (per-64-row producer/consumer)
    k_agg_gemm1<<<AGG_BLOCKS + LIN_BLOCKS, 256, 0, stream>>>(
        row_ptr, esrc, hh_a, a_srcA, a_dstA, bias0, feat_bf,
        p1, ext1, hh_b, a_srcB, a_dstB, cnt1);

    // 5. fused agg1 + out-proj GEMM + LayerNorm (per-128-row producer/consumer)
    k_agg_gemm2<<<AGG_BLOCKS + OUT_BLOCKS, 256, 0, stream>>>(
        row_ptr, esrc, hh_b, a_srcB, a_dstB, bias1, feat_bf,
        p2, b_out, ln_gamma, ln_beta, out, cnt2);
}